// Round 1
// 279.490 us; speedup vs baseline: 1.0060x; 1.0060x over previous
//
#include <hip/hip_runtime.h>
#include <math.h>

// CoPE2d: B=8, HEADS=12, H=W=24, SEQ=576, D=64, NPOS=24
#define NH 12
#define S 576
#define DD 64
#define P 24
#define NROWS 55296                 // rows per unit (x or y)
#define PSTRIDE 32                  // padded bf16 row stride (64 B) for MFMA K=32

typedef unsigned int uint;
typedef unsigned short ushort;
typedef __bf16 bf16x8 __attribute__((ext_vector_type(8)));
typedef float f32x4 __attribute__((ext_vector_type(4)));

__device__ __forceinline__ uint bf16hi_bits(float v) {
    const uint u = __float_as_uint(v);
    return u + 0x7FFFu + ((u >> 16) & 1u);   // rne; take >>16 or &0xFFFF0000
}

// ---------------------------------------------------------------------------
// K01: fused gather + CoPE. One block = (J, hd, b) owns attn rows
// [J*24, J*24+24) of matrix (b,hd). Those 24 rows contain BOTH the x-gate
// diagonal block (cols [24J,24J+24)) and the y-gate comb (col k*24+off of
// row J*24+off), so the gx/gy HBM round-trip (21 MB write + 21 MB read)
// and the whole gather kernel disappear.
// 384 threads: phase0 streams 3456 float4 (9/thread) and filters the 48
// needed cols/row straight into ~5 KB LDS; phases 1-3 are the proven cope
// pipeline on 48 rows (24 x + 24 y) x 8 threads.
// ---------------------------------------------------------------------------
__global__ __launch_bounds__(384) void cope_fused_kernel(
    const float* __restrict__ q,
    const float* __restrict__ attn,
    const float* __restrict__ Ex, const float* __restrict__ Ey,
    __bf16* __restrict__ pxh, __bf16* __restrict__ pxl,
    __bf16* __restrict__ pyh, __bf16* __restrict__ pyl,
    float* __restrict__ sqx, float* __restrict__ sqy)
{
    __shared__ float Et[2][24][68];   // E transposed, both units: Et[u][p][d]
    __shared__ float xg[24][28];      // x gates: xg[rr][jj] = attn[J*24+rr][24J+jj]
    __shared__ float yg[24][25];      // y gates: yg[rr][k]  = attn[J*24+rr][k*24+rr]
    __shared__ float Lr[48][28];      // logits per row (0-23 x, 24-47 y)
    __shared__ float Wr[48][28];      // interp outputs per row

    const int tid = threadIdx.x;
    const int J = blockIdx.x, hd = blockIdx.y, b = blockIdx.z;

    // ---- stage Et (both units) ----
    for (int i = tid; i < 3072; i += 384) {
        const int u = i / 1536, r = i % 1536;
        Et[u][r % 24][r / 24] = (u ? Ey : Ex)[r];
    }

    // ---- phase 0: stream 24 attn rows, filter 48 cols/row into LDS ----
    const float4* src = (const float4*)(attn + (((long)(b * NH + hd) * S + J * 24) * S));
    const int c4lo = 6 * J;                      // x cols [24J,24J+24) = float4 [6J,6J+6)
    #pragma unroll
    for (int t = 0; t < 9; ++t) {
        const int i = t * 384 + tid;             // i < 3456 float4 (24 rows x 144)
        const int rr = i / 144, c4 = i % 144;
        const float4 v = src[i];
        if (c4 >= c4lo && c4 < c4lo + 6) {
            *(float4*)&xg[rr][(c4 - c4lo) * 4] = v;   // stride 28 -> 16B aligned
        }
        const int rem = (c4 * 4) % 24;
        const int u = (rr - rem + 24) % 24;      // lane within float4 hitting col%24==rr
        if (u < 4) {
            const float sel = (u == 0) ? v.x : (u == 1) ? v.y : (u == 2) ? v.z : v.w;
            yg[rr][(c4 * 4 + u) / 24] = sel;
        }
    }
    __syncthreads();

    // ---- row decode: 48 rows x 8 threads ----
    const int rl = tid >> 3, j = tid & 7;
    const bool is_y = rl >= 24;                  // wave-uniform (waves 0-2 x, 3-5 y)
    const int rr = is_y ? rl - 24 : rl;
    const int hq = is_y ? (rr % 12) : (J % 12);
    const int oq = 2 * hd + (is_y ? rr / 12 : J / 12);
    const int qr = is_y ? (J * 24 + oq) : (oq * 24 + rr);
    const int g  = b * NH + hq;
    const int eu = is_y ? 1 : 0;

    // ---- phase 1: logits for p in {j, j+8, j+16} ----
    const float* qrow = q + ((long)g * S + qr) * DD;
    float a0 = 0.f, a1 = 0.f, a2 = 0.f;
    const int p0 = j, p1 = j + 8, p2 = j + 16;
    #pragma unroll
    for (int d4 = 0; d4 < DD; d4 += 4) {
        const float4 qv = *(const float4*)(qrow + d4);
        const float4 e0 = *(const float4*)&Et[eu][p0][d4];
        const float4 e1 = *(const float4*)&Et[eu][p1][d4];
        const float4 e2 = *(const float4*)&Et[eu][p2][d4];
        a0 = fmaf(qv.x, e0.x, fmaf(qv.y, e0.y, fmaf(qv.z, e0.z, fmaf(qv.w, e0.w, a0))));
        a1 = fmaf(qv.x, e1.x, fmaf(qv.y, e1.y, fmaf(qv.z, e1.z, fmaf(qv.w, e1.w, a1))));
        a2 = fmaf(qv.x, e2.x, fmaf(qv.y, e2.y, fmaf(qv.z, e2.z, fmaf(qv.w, e2.w, a2))));
    }
    Lr[rl][p0] = a0; Lr[rl][p1] = a1; Lr[rl][p2] = a2;
    __syncthreads();

    // ---- phase 2: gates (from LDS now) -> suffix scan -> interp ----
    const float* grow = (is_y ? &yg[rr][0] : &xg[rr][0]) + 3 * j;
    float g0 = grow[0], g1 = grow[1], g2 = grow[2];
    g0 = 1.0f / (1.0f + __expf(-g0));
    g1 = 1.0f / (1.0f + __expf(-g1));
    g2 = 1.0f / (1.0f + __expf(-g2));
    const float s = g0 + g1 + g2;
    float T = s;                                  // inclusive suffix sum over 8 lanes
    #pragma unroll
    for (int d = 1; d < 8; d <<= 1) {
        const float o = __shfl_down(T, d, 8);
        T += (j + d < 8) ? o : 0.0f;
    }
    const float Exc = T - s;                      // exclusive suffix
    float posv[3];
    posv[0] = T;
    posv[1] = g1 + g2 + Exc;
    posv[2] = g2 + Exc;

    float sqp = 0.f;
    #pragma unroll
    for (int m = 0; m < 3; ++m) {
        const float pk  = fminf(posv[m], 23.0f);
        const float pf  = floorf(pk);
        const int   ic  = (int)ceilf(pk);
        const int   ifl = (int)pf;
        const float w   = pk - pf;
        const float o   = Lr[rl][ic] * w + Lr[rl][ifl] * (1.0f - w);
        Wr[rl][3 * j + m] = o;
        sqp += o * o;
    }
    #pragma unroll
    for (int d = 1; d < 8; d <<= 1) {
        const float o = __shfl_down(sqp, d, 8);
        sqp += (j + d < 8) ? o : 0.0f;
    }
    if (j == 0) (is_y ? sqy : sqx)[(long)g * S + qr] = sqp;
    __syncthreads();

    // ---- phase 3: pack hi/lo bf16, 16B per thread, zero the K-pad ----
    // 384 threads = 2 (hi/lo) x 48 rows x 4 segs exactly.
    const int hl = tid / 192, rem3 = tid % 192;
    const int r3 = rem3 >> 2, seg = rem3 & 3;
    const bool isy3 = r3 >= 24;
    const int rr3 = isy3 ? r3 - 24 : r3;
    const int hq3 = isy3 ? (rr3 % 12) : (J % 12);
    const int oq3 = 2 * hd + (isy3 ? rr3 / 12 : J / 12);
    const int qr3 = isy3 ? (J * 24 + oq3) : (oq3 * 24 + rr3);
    const int g3 = b * NH + hq3;
    __bf16* dst = (isy3 ? (hl ? pyl : pyh) : (hl ? pxl : pxh))
                  + ((long)g3 * S + qr3) * PSTRIDE + seg * 8;
    uint pk4[4] = {0u, 0u, 0u, 0u};
    if (seg < 3) {
        ushort hv[8];
        #pragma unroll
        for (int t = 0; t < 8; ++t) {
            const float o = Wr[r3][seg * 8 + t];
            const uint rh = bf16hi_bits(o);
            if (hl == 0) {
                hv[t] = (ushort)(rh >> 16);
            } else {
                const float hif = __uint_as_float(rh & 0xFFFF0000u);
                hv[t] = (ushort)(bf16hi_bits(o - hif) >> 16);
            }
        }
        #pragma unroll
        for (int t = 0; t < 4; ++t)
            pk4[t] = (uint)hv[2 * t] | ((uint)hv[2 * t + 1] << 16);
    }
    *(uint4*)dst = make_uint4(pk4[0], pk4[1], pk4[2], pk4[3]);
}

// ---------------------------------------------------------------------------
// K2: MFMA Gram + cdist + blend. 256 threads = 4 waves = 4 consecutive
// 64x64 tiles of matrix g. Padded 64-B rows -> every frag load is a fully
// coalesced 1-KB wave load; addressing is add-only. (unchanged this round)
// ---------------------------------------------------------------------------
__global__ __launch_bounds__(256) void dist_kernel(
    const __bf16* __restrict__ pxh, const __bf16* __restrict__ pxl,
    const __bf16* __restrict__ pyh, const __bf16* __restrict__ pyl,
    const float* __restrict__ sqx, const float* __restrict__ sqy,
    const float* __restrict__ wxp, float* __restrict__ out)
{
    const int tid = threadIdx.x;
    const int w = tid >> 6, lane = tid & 63;
    const int til = blockIdx.x * 4 + w;
    if (til >= 81) return;
    const int g = blockIdx.y;
    const int tn = til / 9, tm = til % 9;
    const int lm = lane & 15, kg = lane >> 4;
    const float wx = wxp[0], wyc = 1.0f - wx;
    const long gb = (long)g * S;

    // persistent B frags (m-side): rows tm*64 + nt*16 + lm
    bf16x8 xbh[4], xbl[4], ybh[4], ybl[4];
    float smx[4], smy[4];
    #pragma unroll
    for (int nt = 0; nt < 4; ++nt) {
        const int row = tm * 64 + nt * 16 + lm;
        const long rb = (gb + row) * PSTRIDE + kg * 8;
        xbh[nt] = *(const bf16x8*)(pxh + rb);
        xbl[nt] = *(const bf16x8*)(pxl + rb);
        ybh[nt] = *(const bf16x8*)(pyh + rb);
        ybl[nt] = *(const bf16x8*)(pyl + rb);
        smx[nt] = sqx[gb + row];
        smy[nt] = sqy[gb + row];
    }

    #pragma unroll
    for (int mt = 0; mt < 4; ++mt) {
        const int arow = tn * 64 + mt * 16 + lm;
        const long ra = (gb + arow) * PSTRIDE + kg * 8;
        const bf16x8 xah = *(const bf16x8*)(pxh + ra);
        const bf16x8 xal = *(const bf16x8*)(pxl + ra);
        const bf16x8 yah = *(const bf16x8*)(pyh + ra);
        const bf16x8 yal = *(const bf16x8*)(pyl + ra);
        float snx[4], sny[4];
        #pragma unroll
        for (int rg = 0; rg < 4; ++rg) {
            const int r = tn * 64 + mt * 16 + kg * 4 + rg;
            snx[rg] = sqx[gb + r];
            sny[rg] = sqy[gb + r];
        }
        #pragma unroll
        for (int nt = 0; nt < 4; ++nt) {
            f32x4 ax = {0.f, 0.f, 0.f, 0.f};
            ax = __builtin_amdgcn_mfma_f32_16x16x32_bf16(xah, xbh[nt], ax, 0, 0, 0);
            ax = __builtin_amdgcn_mfma_f32_16x16x32_bf16(xah, xbl[nt], ax, 0, 0, 0);
            ax = __builtin_amdgcn_mfma_f32_16x16x32_bf16(xal, xbh[nt], ax, 0, 0, 0);
            f32x4 ay = {0.f, 0.f, 0.f, 0.f};
            ay = __builtin_amdgcn_mfma_f32_16x16x32_bf16(yah, ybh[nt], ay, 0, 0, 0);
            ay = __builtin_amdgcn_mfma_f32_16x16x32_bf16(yah, ybl[nt], ay, 0, 0, 0);
            ay = __builtin_amdgcn_mfma_f32_16x16x32_bf16(yal, ybh[nt], ay, 0, 0, 0);
            #pragma unroll
            for (int rg = 0; rg < 4; ++rg) {
                const int row = tn * 64 + mt * 16 + kg * 4 + rg;
                const int col = tm * 64 + nt * 16 + lm;
                const float d2x = fmaxf(fmaf(-2.0f, ax[rg], snx[rg] + smx[nt]), 0.0f);
                const float d2y = fmaxf(fmaf(-2.0f, ay[rg], sny[rg] + smy[nt]), 0.0f);
                const float dx = __builtin_amdgcn_sqrtf(d2x);
                const float dy = __builtin_amdgcn_sqrtf(d2y);
                out[(gb + row) * S + col] = fmaf(wx, dx, wyc * dy);
            }
        }
    }
}

// ---------------------------------------------------------------------------
extern "C" void kernel_launch(void* const* d_in, const int* in_sizes, int n_in,
                              void* d_out, int out_size, void* d_ws, size_t ws_size,
                              hipStream_t stream) {
    const float* q    = (const float*)d_in[0];
    const float* attn = (const float*)d_in[1];
    const float* Ex   = (const float*)d_in[2];
    const float* Ey   = (const float*)d_in[3];
    const float* wxp  = (const float*)d_in[4];
    float* out = (float*)d_out;

    // workspace: pxh|pxl|pyh|pyl (bf16, 32-stride) | sqx|sqy
    __bf16* pxh = (__bf16*)d_ws;
    __bf16* pxl = pxh + (long)NROWS * PSTRIDE;
    __bf16* pyh = pxl + (long)NROWS * PSTRIDE;
    __bf16* pyl = pyh + (long)NROWS * PSTRIDE;
    float* sqx = (float*)(pyl + (long)NROWS * PSTRIDE);
    float* sqy = sqx + NROWS;

    cope_fused_kernel<<<dim3(24, NH, 8), 384, 0, stream>>>(
        q, attn, Ex, Ey, pxh, pxl, pyh, pyl, sqx, sqy);
    dist_kernel<<<dim3(21, 96), 256, 0, stream>>>(pxh, pxl, pyh, pyl,
                                                  sqx, sqy, wxp, out);
}